// Round 1
// baseline (243.577 us; speedup 1.0000x reference)
//
#include <hip/hip_runtime.h>

// Problem constants (from the reference):
//   BS=1024, NSEQ=32 (==SPO_NSEQ), NUM_BOX=128, NUM_CTX=5, MAXC=4, L = in_sizes[6]/BS
constexpr int kBS   = 1024;
constexpr int kNSEQ = 32;
constexpr int kNBOX = 128;
constexpr int kNCTX = 5;
constexpr int kMAXC = 4;

// Kernel 1: out = ent_attn (the compute kernel then overwrites parent rows).
__global__ __launch_bounds__(256) void copy_f4(const float4* __restrict__ s,
                                               float4* __restrict__ d, int n4) {
    int i = blockIdx.x * 256 + threadIdx.x;
    const int str = gridDim.x * 256;
    for (; i < n4; i += str) d[i] = s[i];
}

// Kernel 2: one block per (b, it) pair; 128 threads = one thread per box k.
// Key insight: every (it,b) update reads only ORIGINAL ent_attn rows (parents are
// processed in ascending node order, children always have larger indices, each
// parent row is written exactly once) -> all pairs are independent.
__global__ __launch_bounds__(128) void propagate(
    const float* __restrict__ ent,   // (BS, NSEQ, NBOX) f32
    const float* __restrict__ spo,   // (BS, NSEQ, NBOX, NCTX) f32
    const int*   __restrict__ ctx,   // (BS, NSEQ, NBOX, NCTX) i32
    const float* __restrict__ roi,   // (BS, NSEQ, NBOX, NCTX) f32 (0/1)
    const int*   __restrict__ cls,   // (BS, NBOX) i32
    const float* __restrict__ woc,   // (BS, NSEQ, NBOX) f32
    const int*   __restrict__ pidx,  // (L, BS)
    const float* __restrict__ pval,  // (L, BS)
    const int*   __restrict__ cidx,  // (L, BS, MAXC)
    const int*   __restrict__ eidx,  // (L, BS, MAXC)
    const int*   __restrict__ fsamp, // (L, BS)
    const int*   __restrict__ fslot, // (L, BS)
    float* __restrict__ out)         // (BS, NSEQ, NBOX)
{
    const int b   = blockIdx.x;
    const int it  = blockIdx.y;
    const int idx = it * kBS + b;
    if (pval[idx] <= 0.0f) return;   // invalid (padded) iteration for this batch

    const int k   = threadIdx.x;     // box index 0..127
    const int p   = pidx[idx];
    const int c0  = cidx[idx * kMAXC];        // only child slot 0 feeds transfer[:,0,:]
    const int e0  = eidx[idx * kMAXC];
    const int fs  = fsamp[idx];
    const int fl  = fslot[idx];
    const int ep  = eidx[(it * kBS + fs) * kMAXC + fl];  // cross-batch edge for upd_cols

    // cls_mask and roi_mask appear squared in the reference; 0/1 -> apply once.
    const int   clsk = cls[b * kNBOX + k];
    const float cm   = (clsk != -1) ? 1.0f : 0.0f;
    const float a    = ent[(b * kNSEQ + c0) * kNBOX + k] * cm;

    const size_t sb = ((size_t)(b * kNSEQ + e0) * kNBOX + k) * kNCTX;
    float part[kNCTX];
    #pragma unroll
    for (int c = 0; c < kNCTX; ++c)
        part[c] = a * spo[sb + c] * roi[sb + c];

    // transfer0[c] = 1e-6 + sum_k part[c][k]  (128-lane reduce: wave shfl + LDS combine)
    #pragma unroll
    for (int off = 32; off >= 1; off >>= 1) {
        #pragma unroll
        for (int c = 0; c < kNCTX; ++c)
            part[c] += __shfl_xor(part[c], off, 64);
    }
    __shared__ float wsum[2][kNCTX];
    __shared__ float wmax[2];
    const int wave = k >> 6;
    if ((k & 63) == 0) {
        #pragma unroll
        for (int c = 0; c < kNCTX; ++c) wsum[wave][c] = part[c];
    }
    __syncthreads();
    float t[kNCTX];
    #pragma unroll
    for (int c = 0; c < kNCTX; ++c) t[c] = wsum[0][c] + wsum[1][c] + 1e-6f;

    // upd_cols[c] = ctx_idx_adjusted[fs, ep, 0, c]; columns are distinct (base + 7c mod 128)
    const int cbase = (fs * kNSEQ + ep) * kNBOX * kNCTX;  // box index 0
    float val = 1e-6f;
    #pragma unroll
    for (int c = 0; c < kNCTX; ++c) {
        if (ctx[cbase + c] == k) val = t[c];
    }

    const int pb  = (b * kNSEQ + p) * kNBOX + k;
    float upd = ent[pb] + val * woc[pb];

    // norm = max_k |upd|; divide only if > 1
    float m = fabsf(upd);
    #pragma unroll
    for (int off = 32; off >= 1; off >>= 1)
        m = fmaxf(m, __shfl_xor(m, off, 64));
    if ((k & 63) == 0) wmax[wave] = m;
    __syncthreads();
    const float norm = fmaxf(wmax[0], wmax[1]);
    if (norm > 1.0f) upd /= norm;
    if (clsk == -1) upd = -1.0f;
    out[pb] = upd;
}

extern "C" void kernel_launch(void* const* d_in, const int* in_sizes, int n_in,
                              void* d_out, int out_size, void* d_ws, size_t ws_size,
                              hipStream_t stream) {
    const float* ent   = (const float*)d_in[0];
    const float* spo   = (const float*)d_in[1];
    const int*   ctx   = (const int*)  d_in[2];
    const float* roi   = (const float*)d_in[3];
    const int*   cls   = (const int*)  d_in[4];
    const float* woc   = (const float*)d_in[5];
    const int*   pidx  = (const int*)  d_in[6];
    const float* pval  = (const float*)d_in[7];
    const int*   cidx  = (const int*)  d_in[8];
    // d_in[9] = child_valid: when parent_valid==1, child_valid[...,0]==1 always -> unused
    const int*   eidx  = (const int*)  d_in[10];
    const int*   fsamp = (const int*)  d_in[11];
    const int*   fslot = (const int*)  d_in[12];
    float* out = (float*)d_out;

    const int L  = in_sizes[6] / kBS;   // depth of the padded traversal
    const int n4 = out_size / 4;

    copy_f4<<<dim3(2048), dim3(256), 0, stream>>>((const float4*)ent, (float4*)out, n4);
    propagate<<<dim3(kBS, L), dim3(128), 0, stream>>>(
        ent, spo, ctx, roi, cls, woc, pidx, pval, cidx, eidx, fsamp, fslot, out);
}